// Round 12
// baseline (331.429 us; speedup 1.0000x reference)
//
#include <hip/hip_runtime.h>
#include <hip/hip_bf16.h>
#include <hip/hip_cooperative_groups.h>
#include <stdint.h>

namespace cg = cooperative_groups;

#define M_DIM 8192
#define N_DIM 1024
#define K_DIM 4096

typedef __bf16 bf16x8 __attribute__((ext_vector_type(8)));
typedef float f32x4 __attribute__((ext_vector_type(4)));
typedef __hip_bfloat16 bf16_t;

__device__ __forceinline__ void gload_lds16(const void* g, void* l) {
  __builtin_amdgcn_global_load_lds(
      (const __attribute__((address_space(1))) void*)g,
      (__attribute__((address_space(3))) void*)l, 16, 0, 0);
}

__device__ __forceinline__ float b2f(unsigned short u) {
  union { unsigned i; float f; } x;
  x.i = ((unsigned)u) << 16;
  return x.f;
}

// Pack one int4 (8 bf16) of the tiled pre-swizzled layout from fp32 source.
__device__ __forceinline__ void pack_one(const float* __restrict__ src,
                                         int4* __restrict__ dst, unsigned t) {
  const unsigned cp = t & 7;
  const unsigned tmp = t >> 3;
  const unsigned r = tmp & 255;
  const unsigned tmp2 = tmp >> 8;
  const unsigned kt = tmp2 & 63;
  const unsigned rt = tmp2 >> 6;
  const unsigned srow = (rt << 8) + r;
  const unsigned k0 = (kt << 6) + ((cp ^ (r & 7)) << 3);
  const float4* s = (const float4*)(src + (size_t)srow * 4096 + k0);
  float4 a = s[0], b = s[1];
  union { bf16_t h[8]; int4 v; } u;
  u.h[0] = __float2bfloat16(a.x); u.h[1] = __float2bfloat16(a.y);
  u.h[2] = __float2bfloat16(a.z); u.h[3] = __float2bfloat16(a.w);
  u.h[4] = __float2bfloat16(b.x); u.h[5] = __float2bfloat16(b.y);
  u.h[6] = __float2bfloat16(b.z); u.h[7] = __float2bfloat16(b.w);
  dst[t] = u.v;
}

__device__ __forceinline__ void stage_half(const char* g, char* smem, int ldsoff, int tid) {
  gload_lds16(g + tid * 16, smem + ldsoff + tid * 16);
  gload_lds16(g + 8192 + tid * 16, smem + ldsoff + 8192 + tid * 16);
}

// ---- r10 gemm body (16x16x32, pipelined reads-at-tail, counted vmcnt) -------
// as a device function; NT=32 (split-K=2), grid 256.
__device__ void gemm_body(const char* __restrict__ pA, const char* __restrict__ pB,
                          bf16_t* __restrict__ V0, bf16_t* __restrict__ V1p,
                          char* smem, int tid, int bid, int nblocks) {
  const int lane = tid & 63, wave = tid >> 6;
  const int wm = wave >> 2, wn = wave & 3;
  const int lrow = lane & 15, lkc = lane >> 4;
  const int NT = 32, ktm = 31;

  const int cpx = nblocks >> 3;
  const int swz = (bid & 7) * cpx + (bid >> 3);
  const int split = swz >> 7;
  const int rem = swz & 127;
  const int mt = rem >> 2, nt = rem & 3;

  const char* Abase = pA + ((size_t)mt * 64 + (size_t)split * NT) * 32768;
  const char* Bbase = pB + ((size_t)nt * 64 + (size_t)split * NT) * 32768;
  bf16_t* V = split ? V1p : V0;

  int colw[2];
  colw[0] = ((lkc) ^ (lrow & 7)) << 4;
  colw[1] = ((4 + lkc) ^ (lrow & 7)) << 4;
  int aRow[4], bRow[2];
  #pragma unroll
  for (int f = 0; f < 4; ++f) aRow[f] = (wm * 64 + f * 16 + lrow) * 128;
  #pragma unroll
  for (int f2 = 0; f2 < 2; ++f2) bRow[f2] = 32768 + (wn * 32 + f2 * 16 + lrow) * 128;

  f32x4 acc[2][4][2][2];
  #pragma unroll
  for (int a0 = 0; a0 < 2; ++a0)
    #pragma unroll
    for (int a1 = 0; a1 < 4; ++a1)
      #pragma unroll
      for (int a2 = 0; a2 < 2; ++a2)
        #pragma unroll
        for (int a3 = 0; a3 < 2; ++a3)
          acc[a0][a1][a2][a3] = (f32x4){0.f, 0.f, 0.f, 0.f};

  stage_half(Abase,         smem, 0, tid);       // Ah0(0)
  stage_half(Bbase,         smem, 32768, tid);   // Bh0(0)
  stage_half(Bbase + 16384, smem, 49152, tid);   // Bh1(0)
  stage_half(Abase + 16384, smem, 16384, tid);   // Ah1(0)
  stage_half(Abase + 32768, smem, 65536, tid);   // Ah0(1)
  asm volatile("s_waitcnt vmcnt(4)" ::: "memory");
  __builtin_amdgcn_sched_barrier(0);
  __builtin_amdgcn_s_barrier();

  bf16x8 aE[4][2], aO[4][2], b0[2][2], b1[2][2];
  #pragma unroll
  for (int f = 0; f < 4; ++f)
    #pragma unroll
    for (int s = 0; s < 2; ++s)
      aE[f][s] = *(const bf16x8*)(smem + aRow[f] + colw[s]);
  #pragma unroll
  for (int f2 = 0; f2 < 2; ++f2)
    #pragma unroll
    for (int s = 0; s < 2; ++s)
      b0[f2][s] = *(const bf16x8*)(smem + bRow[f2] + colw[s]);

  for (int g = 0; g < NT; ++g) {
    const int bb = g & 1, nbf = bb ^ 1;
    char* ab = smem + bb * 65536;
    char* nb = smem + nbf * 65536;
    const char* A1t = Abase + (size_t)((g + 1) & ktm) * 32768;
    const char* B1t = Bbase + (size_t)((g + 1) & ktm) * 32768;
    const char* A2t = Abase + (size_t)((g + 2) & ktm) * 32768;

    // P0: stage Bh0/Bh1(g+1); MFMA M0N0; tail read b1(g); vmcnt(6)
    stage_half(B1t, smem, nbf * 65536 + 32768, tid);
    stage_half(B1t + 16384, smem, nbf * 65536 + 49152, tid);
    __builtin_amdgcn_s_setprio(1);
    #pragma unroll
    for (int f = 0; f < 4; ++f)
      #pragma unroll
      for (int f2 = 0; f2 < 2; ++f2)
        #pragma unroll
        for (int s = 0; s < 2; ++s)
          acc[0][f][0][f2] = __builtin_amdgcn_mfma_f32_16x16x32_bf16(
              aE[f][s], b0[f2][s], acc[0][f][0][f2], 0, 0, 0);
    __builtin_amdgcn_s_setprio(0);
    __builtin_amdgcn_sched_barrier(0);
    #pragma unroll
    for (int f2 = 0; f2 < 2; ++f2)
      #pragma unroll
      for (int s = 0; s < 2; ++s)
        b1[f2][s] = *(const bf16x8*)(ab + bRow[f2] + 16384 + colw[s]);
    asm volatile("s_waitcnt vmcnt(6)" ::: "memory");
    __builtin_amdgcn_sched_barrier(0);
    __builtin_amdgcn_s_barrier();

    // P1: stage Ah1(g+1); MFMA M0N1; tail read aO(g)
    stage_half(A1t + 16384, smem, nbf * 65536 + 16384, tid);
    __builtin_amdgcn_s_setprio(1);
    #pragma unroll
    for (int f = 0; f < 4; ++f)
      #pragma unroll
      for (int f2 = 0; f2 < 2; ++f2)
        #pragma unroll
        for (int s = 0; s < 2; ++s)
          acc[0][f][1][f2] = __builtin_amdgcn_mfma_f32_16x16x32_bf16(
              aE[f][s], b1[f2][s], acc[0][f][1][f2], 0, 0, 0);
    __builtin_amdgcn_s_setprio(0);
    __builtin_amdgcn_sched_barrier(0);
    #pragma unroll
    for (int f = 0; f < 4; ++f)
      #pragma unroll
      for (int s = 0; s < 2; ++s)
        aO[f][s] = *(const bf16x8*)(ab + aRow[f] + 16384 + colw[s]);
    __builtin_amdgcn_sched_barrier(0);
    __builtin_amdgcn_s_barrier();

    // P2: stage Ah0(g+2); MFMA M1N1; vmcnt(8); tail read aE(g+1)
    stage_half(A2t, smem, bb * 65536, tid);
    __builtin_amdgcn_s_setprio(1);
    #pragma unroll
    for (int f = 0; f < 4; ++f)
      #pragma unroll
      for (int f2 = 0; f2 < 2; ++f2)
        #pragma unroll
        for (int s = 0; s < 2; ++s)
          acc[1][f][1][f2] = __builtin_amdgcn_mfma_f32_16x16x32_bf16(
              aO[f][s], b1[f2][s], acc[1][f][1][f2], 0, 0, 0);
    __builtin_amdgcn_s_setprio(0);
    __builtin_amdgcn_sched_barrier(0);
    asm volatile("s_waitcnt vmcnt(8)" ::: "memory");
    #pragma unroll
    for (int f = 0; f < 4; ++f)
      #pragma unroll
      for (int s = 0; s < 2; ++s)
        aE[f][s] = *(const bf16x8*)(nb + aRow[f] + colw[s]);
    __builtin_amdgcn_sched_barrier(0);
    __builtin_amdgcn_s_barrier();

    // P3: MFMA M1N0; vmcnt(4); tail read b0(g+1)
    __builtin_amdgcn_s_setprio(1);
    #pragma unroll
    for (int f = 0; f < 4; ++f)
      #pragma unroll
      for (int f2 = 0; f2 < 2; ++f2)
        #pragma unroll
        for (int s = 0; s < 2; ++s)
          acc[1][f][0][f2] = __builtin_amdgcn_mfma_f32_16x16x32_bf16(
              aO[f][s], b0[f2][s], acc[1][f][0][f2], 0, 0, 0);
    __builtin_amdgcn_s_setprio(0);
    __builtin_amdgcn_sched_barrier(0);
    asm volatile("s_waitcnt vmcnt(4)" ::: "memory");
    #pragma unroll
    for (int f2 = 0; f2 < 2; ++f2)
      #pragma unroll
      for (int s = 0; s < 2; ++s)
        b0[f2][s] = *(const bf16x8*)(nb + bRow[f2] + colw[s]);
    __builtin_amdgcn_sched_barrier(0);
    __builtin_amdgcn_s_barrier();
  }

  // C-write (bf16 partials): col=lane&15, row=(lane>>4)*4+reg (m89-verified).
  const int lq = lane >> 4;
  #pragma unroll
  for (int qm = 0; qm < 2; ++qm)
    #pragma unroll
    for (int f = 0; f < 4; ++f) {
      const int rowg = mt * 256 + qm * 128 + wm * 64 + f * 16 + lq * 4;
      #pragma unroll
      for (int reg = 0; reg < 4; ++reg) {
        bf16_t* Vr = V + (size_t)(rowg + reg) * N_DIM + nt * 256 + wn * 32 + lrow;
        #pragma unroll
        for (int qn = 0; qn < 2; ++qn)
          #pragma unroll
          for (int f2 = 0; f2 < 2; ++f2)
            Vr[qn * 128 + f2 * 16] = __float2bfloat16(acc[qm][f][qn][f2][reg]);
      }
    }
}

// ---- fused cooperative kernel: pack -> gemm -> householder ------------------
__global__ __launch_bounds__(512, 2) void fused(
    const float* __restrict__ enc, const float* __restrict__ W,
    const float* __restrict__ x, const float* __restrict__ bias,
    char* __restrict__ packA, char* __restrict__ packB,
    bf16_t* __restrict__ V0, bf16_t* __restrict__ V1,
    float* __restrict__ out, float* __restrict__ logdet) {
  extern __shared__ char smem[];
  cg::grid_group grid = cg::this_grid();
  const int tid = threadIdx.x;
  const int bid = blockIdx.x;

  // ---- Phase A: pack enc+W into tiled pre-swizzled bf16 (grid-strided) -----
  {
    const unsigned base = (unsigned)bid * 512u + (unsigned)tid;
    #pragma unroll 4
    for (int it = 0; it < 36; ++it) {
      unsigned gt = (unsigned)it * 131072u + base;   // 36*131072 = 4718592 total
      if (gt < 4194304u) pack_one(enc, (int4*)packA, gt);
      else               pack_one(W,   (int4*)packB, gt - 4194304u);
    }
  }
  __threadfence();
  grid.sync();

  // ---- Phase B: gemm (r10 body) --------------------------------------------
  gemm_body(packA, packB, V0, V1, smem, tid, bid, (int)gridDim.x);
  __threadfence();
  grid.sync();

  // ---- Phase C: Householder epilogue, 2 rows per iteration -----------------
  {
    const int half = tid >> 8;      // which of the 2 concurrent rows
    const int t2 = tid & 255;       // lane within row (256 x float4)
    float* sred = (float*)smem;     // [2][8]
    for (int it = 0; it < 16; ++it) {
      const int row = bid * 32 + it * 2 + half;
      ushort4 u0 = ((const ushort4*)((const unsigned short*)V0 + (size_t)row * N_DIM))[t2];
      ushort4 u1 = ((const ushort4*)((const unsigned short*)V1 + (size_t)row * N_DIM))[t2];
      float4 bb = ((const float4*)bias)[t2];
      float4 v;
      v.x = b2f(u0.x) + b2f(u1.x) + bb.x;
      v.y = b2f(u0.y) + b2f(u1.y) + bb.y;
      v.z = b2f(u0.z) + b2f(u1.z) + bb.z;
      v.w = b2f(u0.w) + b2f(u1.w) + bb.w;
      float4 xx = ((const float4*)(x + (size_t)row * N_DIM))[t2];

      float dot = v.x * xx.x + v.y * xx.y + v.z * xx.z + v.w * xx.w;
      float nsq = v.x * v.x + v.y * v.y + v.z * v.z + v.w * v.w;
      #pragma unroll
      for (int off = 32; off > 0; off >>= 1) {
        dot += __shfl_down(dot, off);
        nsq += __shfl_down(nsq, off);
      }
      if ((t2 & 63) == 0) {
        sred[half * 8 + (t2 >> 6)] = dot;
        sred[half * 8 + 4 + (t2 >> 6)] = nsq;
      }
      __syncthreads();
      dot = sred[half * 8] + sred[half * 8 + 1] + sred[half * 8 + 2] + sred[half * 8 + 3];
      nsq = sred[half * 8 + 4] + sred[half * 8 + 5] + sred[half * 8 + 6] + sred[half * 8 + 7];
      const float f = 2.0f * dot / sqrtf(nsq);
      float4 o;
      o.x = xx.x - f * v.x;
      o.y = xx.y - f * v.y;
      o.z = xx.z - f * v.z;
      o.w = xx.w - f * v.w;
      ((float4*)(out + (size_t)row * N_DIM))[t2] = o;
      if (t2 == 0 && half == 0) logdet[row] = 0.0f;
      if (t2 == 0 && half == 1) logdet[row] = 0.0f;
      __syncthreads();
    }
  }
}

// ================= fallback (non-cooperative r10 path, nsplit=1) =============
__global__ __launch_bounds__(256) void pack_both(const float* __restrict__ enc,
                                                 const float* __restrict__ W,
                                                 int4* __restrict__ pA,
                                                 int4* __restrict__ pB) {
  const unsigned gtid = blockIdx.x * 256 + threadIdx.x;
  if (gtid < 4194304u) pack_one(enc, pA, gtid);
  else                 pack_one(W,   pB, gtid - 4194304u);
}

__global__ __launch_bounds__(512, 2) void gemm8(
    const char* __restrict__ pA, const char* __restrict__ pB,
    bf16_t* __restrict__ V0, bf16_t* __restrict__ V1p, int NT) {
  extern __shared__ char smem[];
  // NT==64 single-split fallback: reuse gemm_body only valid for NT=32 grid 256;
  // for the fallback we run the generic path below.
  const int tid = threadIdx.x;
  const int lane = tid & 63, wave = tid >> 6;
  const int wm = wave >> 2, wn = wave & 3;
  const int lrow = lane & 15, lkc = lane >> 4;
  const int cpx = (int)gridDim.x >> 3;
  const int swz = ((int)blockIdx.x & 7) * cpx + ((int)blockIdx.x >> 3);
  const int rem = swz & 127;
  const int mt = rem >> 2, nt = rem & 3;
  const int ktm = NT - 1;
  const char* Abase = pA + (size_t)mt * 64 * 32768;
  const char* Bbase = pB + (size_t)nt * 64 * 32768;
  bf16_t* V = V0;
  (void)V1p;

  int colw[2];
  colw[0] = ((lkc) ^ (lrow & 7)) << 4;
  colw[1] = ((4 + lkc) ^ (lrow & 7)) << 4;
  int aRow[4], bRow[2];
  #pragma unroll
  for (int f = 0; f < 4; ++f) aRow[f] = (wm * 64 + f * 16 + lrow) * 128;
  #pragma unroll
  for (int f2 = 0; f2 < 2; ++f2) bRow[f2] = 32768 + (wn * 32 + f2 * 16 + lrow) * 128;

  f32x4 acc[2][4][2][2];
  #pragma unroll
  for (int a0 = 0; a0 < 2; ++a0)
    #pragma unroll
    for (int a1 = 0; a1 < 4; ++a1)
      #pragma unroll
      for (int a2 = 0; a2 < 2; ++a2)
        #pragma unroll
        for (int a3 = 0; a3 < 2; ++a3)
          acc[a0][a1][a2][a3] = (f32x4){0.f, 0.f, 0.f, 0.f};

  stage_half(Abase,         smem, 0, tid);
  stage_half(Bbase,         smem, 32768, tid);
  stage_half(Bbase + 16384, smem, 49152, tid);
  stage_half(Abase + 16384, smem, 16384, tid);
  stage_half(Abase + 32768, smem, 65536, tid);
  asm volatile("s_waitcnt vmcnt(4)" ::: "memory");
  __builtin_amdgcn_s_barrier();

  bf16x8 aE[4][2], aO[4][2], b0[2][2], b1[2][2];
  #pragma unroll
  for (int f = 0; f < 4; ++f)
    #pragma unroll
    for (int s = 0; s < 2; ++s)
      aE[f][s] = *(const bf16x8*)(smem + aRow[f] + colw[s]);
  #pragma unroll
  for (int f2 = 0; f2 < 2; ++f2)
    #pragma unroll
    for (int s = 0; s < 2; ++s)
      b0[f2][s] = *(const bf16x8*)(smem + bRow[f2] + colw[s]);

  for (int g = 0; g < NT; ++g) {
    const int bb = g & 1, nbf = bb ^ 1;
    char* ab = smem + bb * 65536;
    char* nb = smem + nbf * 65536;
    const char* A1t = Abase + (size_t)((g + 1) & ktm) * 32768;
    const char* B1t = Bbase + (size_t)((g + 1) & ktm) * 32768;
    const char* A2t = Abase + (size_t)((g + 2) & ktm) * 32768;

    stage_half(B1t, smem, nbf * 65536 + 32768, tid);
    stage_half(B1t + 16384, smem, nbf * 65536 + 49152, tid);
    #pragma unroll
    for (int f = 0; f < 4; ++f)
      #pragma unroll
      for (int f2 = 0; f2 < 2; ++f2)
        #pragma unroll
        for (int s = 0; s < 2; ++s)
          acc[0][f][0][f2] = __builtin_amdgcn_mfma_f32_16x16x32_bf16(
              aE[f][s], b0[f2][s], acc[0][f][0][f2], 0, 0, 0);
    #pragma unroll
    for (int f2 = 0; f2 < 2; ++f2)
      #pragma unroll
      for (int s = 0; s < 2; ++s)
        b1[f2][s] = *(const bf16x8*)(ab + bRow[f2] + 16384 + colw[s]);
    asm volatile("s_waitcnt vmcnt(6)" ::: "memory");
    __builtin_amdgcn_s_barrier();

    stage_half(A1t + 16384, smem, nbf * 65536 + 16384, tid);
    #pragma unroll
    for (int f = 0; f < 4; ++f)
      #pragma unroll
      for (int f2 = 0; f2 < 2; ++f2)
        #pragma unroll
        for (int s = 0; s < 2; ++s)
          acc[0][f][1][f2] = __builtin_amdgcn_mfma_f32_16x16x32_bf16(
              aE[f][s], b1[f2][s], acc[0][f][1][f2], 0, 0, 0);
    #pragma unroll
    for (int f = 0; f < 4; ++f)
      #pragma unroll
      for (int s = 0; s < 2; ++s)
        aO[f][s] = *(const bf16x8*)(ab + aRow[f] + 16384 + colw[s]);
    __builtin_amdgcn_s_barrier();

    stage_half(A2t, smem, bb * 65536, tid);
    #pragma unroll
    for (int f = 0; f < 4; ++f)
      #pragma unroll
      for (int f2 = 0; f2 < 2; ++f2)
        #pragma unroll
        for (int s = 0; s < 2; ++s)
          acc[1][f][1][f2] = __builtin_amdgcn_mfma_f32_16x16x32_bf16(
              aO[f][s], b1[f2][s], acc[1][f][1][f2], 0, 0, 0);
    asm volatile("s_waitcnt vmcnt(8)" ::: "memory");
    #pragma unroll
    for (int f = 0; f < 4; ++f)
      #pragma unroll
      for (int s = 0; s < 2; ++s)
        aE[f][s] = *(const bf16x8*)(nb + aRow[f] + colw[s]);
    __builtin_amdgcn_s_barrier();

    #pragma unroll
    for (int f = 0; f < 4; ++f)
      #pragma unroll
      for (int f2 = 0; f2 < 2; ++f2)
        #pragma unroll
        for (int s = 0; s < 2; ++s)
          acc[1][f][0][f2] = __builtin_amdgcn_mfma_f32_16x16x32_bf16(
              aO[f][s], b0[f2][s], acc[1][f][0][f2], 0, 0, 0);
    asm volatile("s_waitcnt vmcnt(4)" ::: "memory");
    #pragma unroll
    for (int f2 = 0; f2 < 2; ++f2)
      #pragma unroll
      for (int s = 0; s < 2; ++s)
        b0[f2][s] = *(const bf16x8*)(nb + bRow[f2] + colw[s]);
    __builtin_amdgcn_s_barrier();
  }

  const int lq = lane >> 4;
  #pragma unroll
  for (int qm = 0; qm < 2; ++qm)
    #pragma unroll
    for (int f = 0; f < 4; ++f) {
      const int rowg = mt * 256 + qm * 128 + wm * 64 + f * 16 + lq * 4;
      #pragma unroll
      for (int reg = 0; reg < 4; ++reg) {
        bf16_t* Vr = V + (size_t)(rowg + reg) * N_DIM + nt * 256 + wn * 32 + lrow;
        #pragma unroll
        for (int qn = 0; qn < 2; ++qn)
          #pragma unroll
          for (int f2 = 0; f2 < 2; ++f2)
            Vr[qn * 128 + f2 * 16] = __float2bfloat16(acc[qm][f][qn][f2][reg]);
      }
    }
}

__global__ __launch_bounds__(256) void householder_ep(
    const float* __restrict__ x, const float* __restrict__ bias,
    const unsigned short* __restrict__ V0b, const unsigned short* __restrict__ V1b,
    float* __restrict__ out, float* __restrict__ logdet) {
  const int row = blockIdx.x;
  const int t = threadIdx.x;
  ushort4 u0 = ((const ushort4*)(V0b + (size_t)row * N_DIM))[t];
  float4 v;
  v.x = b2f(u0.x); v.y = b2f(u0.y); v.z = b2f(u0.z); v.w = b2f(u0.w);
  if (V1b) {
    ushort4 u1 = ((const ushort4*)(V1b + (size_t)row * N_DIM))[t];
    v.x += b2f(u1.x); v.y += b2f(u1.y); v.z += b2f(u1.z); v.w += b2f(u1.w);
  }
  float4 bb = ((const float4*)bias)[t];
  v.x += bb.x; v.y += bb.y; v.z += bb.z; v.w += bb.w;
  float4 xx = ((const float4*)(x + (size_t)row * N_DIM))[t];

  float dot = v.x * xx.x + v.y * xx.y + v.z * xx.z + v.w * xx.w;
  float nsq = v.x * v.x + v.y * v.y + v.z * v.z + v.w * v.w;
  #pragma unroll
  for (int off = 32; off > 0; off >>= 1) {
    dot += __shfl_down(dot, off);
    nsq += __shfl_down(nsq, off);
  }
  __shared__ float sd[4], sn[4];
  if ((t & 63) == 0) { sd[t >> 6] = dot; sn[t >> 6] = nsq; }
  __syncthreads();
  dot = sd[0] + sd[1] + sd[2] + sd[3];
  nsq = sn[0] + sn[1] + sn[2] + sn[3];
  const float f = 2.0f * dot / sqrtf(nsq);
  float4 o;
  o.x = xx.x - f * v.x;
  o.y = xx.y - f * v.y;
  o.z = xx.z - f * v.z;
  o.w = xx.w - f * v.w;
  ((float4*)(out + (size_t)row * N_DIM))[t] = o;
  if (t == 0) logdet[row] = 0.0f;
}

extern "C" void kernel_launch(void* const* d_in, const int* in_sizes, int n_in,
                              void* d_out, int out_size, void* d_ws, size_t ws_size,
                              hipStream_t stream) {
  const float* x   = (const float*)d_in[0];   // [8192,1024]
  const float* enc = (const float*)d_in[1];   // [8192,4096]
  const float* W   = (const float*)d_in[2];   // [1024,4096]
  const float* b   = (const float*)d_in[3];   // [1024]

  float* out    = (float*)d_out;
  float* logdet = out + (size_t)M_DIM * N_DIM;

  char*   packA = (char*)d_ws;                              // 64 MB
  char*   packB = packA + (size_t)64 * 1024 * 1024;         //  8 MB
  bf16_t* V0b   = (bf16_t*)(packB + (size_t)8 * 1024 * 1024);   // 16 MB
  bf16_t* V1b   = V0b + (size_t)M_DIM * N_DIM;                  // 16 MB

  const size_t need2 = (size_t)104 * 1024 * 1024;

  if (ws_size >= need2) {
    hipFuncSetAttribute((const void*)fused, hipFuncAttributeMaxDynamicSharedMemorySize, 131072);
    void* kargs[] = {(void*)&enc, (void*)&W, (void*)&x, (void*)&b,
                     (void*)&packA, (void*)&packB, (void*)&V0b, (void*)&V1b,
                     (void*)&out, (void*)&logdet};
    hipLaunchCooperativeKernel((const void*)fused, dim3(256), dim3(512),
                               kargs, 131072, stream);
  } else {
    pack_both<<<18432, 256, 0, stream>>>(enc, W, (int4*)packA, (int4*)packB);
    hipFuncSetAttribute((const void*)gemm8, hipFuncAttributeMaxDynamicSharedMemorySize, 131072);
    gemm8<<<dim3(128), 512, 131072, stream>>>(packA, packB, V0b, nullptr, 64);
    householder_ep<<<M_DIM, 256, 0, stream>>>(
        x, b, (const unsigned short*)V0b, nullptr, out, logdet);
  }
}